// Round 7
// baseline (2937.352 us; speedup 1.0000x reference)
//
#include <hip/hip_runtime.h>
#include <hip/hip_bf16.h>

typedef unsigned short u16;
typedef unsigned int   u32;

#define BB   2
#define NN   2048
#define HS   16
#define DH   64
#define NM   16
#define JT   2064   // NM + NN
#define DIM  1024

__device__ __forceinline__ float lo16(u32 u)  { return __uint_as_float(u << 16); }
__device__ __forceinline__ float hi16(u32 u)  { return __uint_as_float(u & 0xffff0000u); }
__device__ __forceinline__ float bfval(u16 u) { return __uint_as_float(((u32)u) << 16); }
__device__ __forceinline__ u16 f2bf(float f)
{
    __hip_bfloat16 h = __float2bfloat16(f);
    return *(u16*)&h;
}

typedef __bf16 bf16x8 __attribute__((ext_vector_type(8)));
typedef float  f32x4  __attribute__((ext_vector_type(4)));

// ---------------------------------------------------------------------------
// Exact-f32 GEMM via 6-pass bf16 split MFMA:
//   x = xh + xm + xl (exact, 24+ mantissa bits); keep hh,hm,mh,mm,hl,lh
//   (dropped terms <= 2^-27 rel). C[4096][1024] = A(f32) @ B(f32).
// tile 128x64, 256 threads (4 waves).
// mode 0: f32 scatter to [b][h][2048][64] head layout (K/V)
// mode 1: f32 row-major C = acc + bias (Q -> d_out)
// ---------------------------------------------------------------------------
__global__ __launch_bounds__(256) void gemm_kernel(
    const float* __restrict__ A, const float* __restrict__ Bw,
    float* __restrict__ dstf, const float* __restrict__ bias, int mode)
{
    __shared__ __align__(16) u16 a_h[128][32];
    __shared__ __align__(16) u16 a_m[128][32];
    __shared__ __align__(16) u16 a_l[128][32];
    __shared__ __align__(16) u16 b_hT[64][32];
    __shared__ __align__(16) u16 b_mT[64][32];
    __shared__ __align__(16) u16 b_lT[64][32];

    const int tid  = threadIdx.x;
    const int m0   = blockIdx.x * 128;
    const int n0   = blockIdx.y * 64;
    const int wave = tid >> 6, lane = tid & 63;
    const int ln16 = lane & 15, quad = lane >> 4;

    const int arow = tid >> 1;            // 0..127
    const int ac   = (tid & 1) * 16;      // 0 or 16
    const int brow = tid >> 3;            // 0..31
    const int bc   = (tid & 7) * 8;       // 0..56

    f32x4 acc[8] = {};

    for (int k0 = 0; k0 < 1024; k0 += 32) {
        float av[16];
        {
            const float4* ap = (const float4*)&A[(size_t)(m0 + arow) * 1024 + k0 + ac];
            *(float4*)&av[0]  = ap[0]; *(float4*)&av[4]  = ap[1];
            *(float4*)&av[8]  = ap[2]; *(float4*)&av[12] = ap[3];
        }
        float bv[8];
        {
            const float4* bp = (const float4*)&Bw[(size_t)(k0 + brow) * 1024 + n0 + bc];
            *(float4*)&bv[0] = bp[0]; *(float4*)&bv[4] = bp[1];
        }
        u16 ah[16], am[16], al[16], bh[8], bm[8], bl[8];
        #pragma unroll
        for (int e = 0; e < 16; ++e) {
            ah[e] = f2bf(av[e]);
            float d1 = av[e] - bfval(ah[e]);
            am[e] = f2bf(d1);
            al[e] = f2bf(d1 - bfval(am[e]));
        }
        #pragma unroll
        for (int e = 0; e < 8; ++e) {
            bh[e] = f2bf(bv[e]);
            float d1 = bv[e] - bfval(bh[e]);
            bm[e] = f2bf(d1);
            bl[e] = f2bf(d1 - bfval(bm[e]));
        }
        __syncthreads();
        *(uint4*)&a_h[arow][ac]     = ((uint4*)ah)[0];
        *(uint4*)&a_h[arow][ac + 8] = ((uint4*)ah)[1];
        *(uint4*)&a_m[arow][ac]     = ((uint4*)am)[0];
        *(uint4*)&a_m[arow][ac + 8] = ((uint4*)am)[1];
        *(uint4*)&a_l[arow][ac]     = ((uint4*)al)[0];
        *(uint4*)&a_l[arow][ac + 8] = ((uint4*)al)[1];
        #pragma unroll
        for (int e = 0; e < 8; ++e) {
            b_hT[bc + e][brow] = bh[e];
            b_mT[bc + e][brow] = bm[e];
            b_lT[bc + e][brow] = bl[e];
        }
        __syncthreads();

        bf16x8 a0h = *(const bf16x8*)&a_h[wave * 32 + ln16][quad * 8];
        bf16x8 a0m = *(const bf16x8*)&a_m[wave * 32 + ln16][quad * 8];
        bf16x8 a0l = *(const bf16x8*)&a_l[wave * 32 + ln16][quad * 8];
        bf16x8 a1h = *(const bf16x8*)&a_h[wave * 32 + 16 + ln16][quad * 8];
        bf16x8 a1m = *(const bf16x8*)&a_m[wave * 32 + 16 + ln16][quad * 8];
        bf16x8 a1l = *(const bf16x8*)&a_l[wave * 32 + 16 + ln16][quad * 8];
        #pragma unroll
        for (int c = 0; c < 4; ++c) {
            bf16x8 bh_ = *(const bf16x8*)&b_hT[c * 16 + ln16][quad * 8];
            bf16x8 bm_ = *(const bf16x8*)&b_mT[c * 16 + ln16][quad * 8];
            bf16x8 bl_ = *(const bf16x8*)&b_lT[c * 16 + ln16][quad * 8];
            // small terms first for accumulation accuracy
            acc[c]     = __builtin_amdgcn_mfma_f32_16x16x32_bf16(a0m, bm_, acc[c],     0, 0, 0);
            acc[c]     = __builtin_amdgcn_mfma_f32_16x16x32_bf16(a0h, bl_, acc[c],     0, 0, 0);
            acc[c]     = __builtin_amdgcn_mfma_f32_16x16x32_bf16(a0l, bh_, acc[c],     0, 0, 0);
            acc[c]     = __builtin_amdgcn_mfma_f32_16x16x32_bf16(a0h, bm_, acc[c],     0, 0, 0);
            acc[c]     = __builtin_amdgcn_mfma_f32_16x16x32_bf16(a0m, bh_, acc[c],     0, 0, 0);
            acc[c]     = __builtin_amdgcn_mfma_f32_16x16x32_bf16(a0h, bh_, acc[c],     0, 0, 0);
            acc[4 + c] = __builtin_amdgcn_mfma_f32_16x16x32_bf16(a1m, bm_, acc[4 + c], 0, 0, 0);
            acc[4 + c] = __builtin_amdgcn_mfma_f32_16x16x32_bf16(a1h, bl_, acc[4 + c], 0, 0, 0);
            acc[4 + c] = __builtin_amdgcn_mfma_f32_16x16x32_bf16(a1l, bh_, acc[4 + c], 0, 0, 0);
            acc[4 + c] = __builtin_amdgcn_mfma_f32_16x16x32_bf16(a1h, bm_, acc[4 + c], 0, 0, 0);
            acc[4 + c] = __builtin_amdgcn_mfma_f32_16x16x32_bf16(a1m, bh_, acc[4 + c], 0, 0, 0);
            acc[4 + c] = __builtin_amdgcn_mfma_f32_16x16x32_bf16(a1h, bh_, acc[4 + c], 0, 0, 0);
        }
    }

    #pragma unroll
    for (int hf = 0; hf < 2; ++hf) {
        #pragma unroll
        for (int c = 0; c < 4; ++c) {
            #pragma unroll
            for (int r = 0; r < 4; ++r) {
                int row = m0 + wave * 32 + hf * 16 + quad * 4 + r;
                int col = n0 + c * 16 + ln16;
                float v = acc[hf * 4 + c][r];
                if (mode == 1) {
                    if (bias) v += bias[col];
                    dstf[(size_t)row * 1024 + col] = v;
                } else {
                    int b = row >> 11, i = row & 2047;
                    int h = col >> 6, d = col & 63;
                    dstf[(((size_t)(b * HS + h)) * NN + i) * DH + d] = v;
                }
            }
        }
    }
}

// ---------------------------------------------------------------------------
// Fused attention: one block per (b, 16-query rows). Full-f32 selection AND
// value paths (only arows/Wo are bf16 in the fused out-projection).
//  - K tile jt==0 comes straight from mem_k input; later tiles from k_ws.
//  - PV gathers f32 V: j<16 from mem_v input, else v_ws.
// LDS: 13312 floats = 53248 B.
// ---------------------------------------------------------------------------
__global__ __launch_bounds__(256) void attn_kernel(
    const float* __restrict__ k_ws, const float* __restrict__ v_ws,
    const float* __restrict__ mem_k, const float* __restrict__ mem_v,
    const float* __restrict__ pre,  const float* __restrict__ post,
    const float* __restrict__ Wo,   const float* __restrict__ bo,
    float* __restrict__ out)
{
    __shared__ __align__(16) float fsm[13312];
    float* q_c4  = fsm;            // [4][16][68] f32
    float* k_c4  = fsm + 4352;     // [4][16][68] f32
    float* dotsm = fsm + 8704;     // [4096]: scores [kk][ti][tj]; later w/j park
    float* pp    = fsm + 12800;    // [256] pre_proj
    float* pp2   = fsm + 13056;    // [256] post_proj

    const int tid = threadIdx.x;
    const int b   = blockIdx.y;
    const int i0  = blockIdx.x * 16;

    pp[tid]  = pre[tid];
    pp2[tid] = post[tid];

    const float* qsrc = out + (size_t)(b * NN + i0) * DIM;

    const int ti = tid >> 4, tj = tid & 15;     // dot-compute mapping
    const int kk_r = tid & 15, ti_r = tid >> 4; // top-k row mapping

    float tv[8];
    int   tx[8];
    #pragma unroll
    for (int t = 0; t < 8; ++t) { tv[t] = -1e30f; tx[t] = 0; }
    const int jlim = NM + i0 + ti_r;            // inclusive causal limit
    const int ntiles = blockIdx.x + 2;          // covers j <= i0 + 31

    for (int jt = 0; jt < ntiles; ++jt) {
        // zero own mixed-score slots (prev top-8 readers drained by loop-end barrier)
        #pragma unroll
        for (int kk = 0; kk < 16; ++kk) dotsm[kk * 256 + ti * 16 + tj] = 0.f;

        for (int c4 = 0; c4 < 4; ++c4) {
            __syncthreads();  // prev dot-phase q/k LDS reads done (publishes pp first time)
            #pragma unroll
            for (int p = 0; p < 4; ++p) {
                int f = tid + p * 256;          // 0..1023 float4 slots
                int row = f >> 4;               // hh*16 + r
                int c4i = f & 15;
                int hh = row >> 4, r = row & 15;
                float4 qa = *(const float4*)&qsrc[(size_t)r * DIM + (c4 * 4 + hh) * 64 + c4i * 4];
                *(float4*)&q_c4[row * 68 + c4i * 4] = qa;
                float4 ka;
                if (jt == 0)
                    ka = *(const float4*)&mem_k[((c4 * 4 + hh) * NM + r) * DH + c4i * 4];
                else
                    ka = *(const float4*)
                        &k_ws[((size_t)(b * HS + c4 * 4 + hh) * NN + (jt - 1) * 16 + r) * DH + c4i * 4];
                *(float4*)&k_c4[row * 68 + c4i * 4] = ka;
            }
            __syncthreads();

            float part[16];
            #pragma unroll
            for (int kk = 0; kk < 16; ++kk) part[kk] = 0.f;
            for (int hh = 0; hh < 4; ++hh) {
                const float* qr = &q_c4[(hh * 16 + ti) * 68];
                const float* kr = &k_c4[(hh * 16 + tj) * 68];
                float dot = 0.f;
                #pragma unroll
                for (int d = 0; d < 64; ++d) dot += qr[d] * kr[d];
                dot *= 0.125f;
                dot = (dot == dot) ? dot : -1e30f;   // NaN scrub (diagnostic)
                const int h = c4 * 4 + hh;
                #pragma unroll
                for (int kk = 0; kk < 16; ++kk) part[kk] += pp[h * 16 + kk] * dot;
            }
            #pragma unroll
            for (int kk = 0; kk < 16; ++kk) dotsm[kk * 256 + ti * 16 + tj] += part[kk];
        }
        __syncthreads();  // mixed scores visible to top-8 readers

        // top-8 update for row (kk_r, ti_r); rotate tj start by kk_r
        for (int s = 0; s < 16; ++s) {
            int tjj = (s + kk_r) & 15;
            int j = jt * 16 + tjj;
            if (j <= jlim) {
                float c = dotsm[kk_r * 256 + ti_r * 16 + tjj];
                if (c > tv[7]) {
                    #pragma unroll
                    for (int t = 7; t >= 1; --t) {
                        if (c > tv[t - 1])      { tv[t] = tv[t - 1]; tx[t] = tx[t - 1]; }
                        else if (c > tv[t])     { tv[t] = c;         tx[t] = j; }
                    }
                    if (c > tv[0]) { tv[0] = c; tx[0] = j; }
                }
            }
        }
        __syncthreads();  // top-8 reads done before next tile's zeroing
    }

    // sparse softmax over the 8 kept entries (row always has >= 17 candidates)
    float m = tv[0];
    float wv[8], wsum = 0.f;
    #pragma unroll
    for (int t = 0; t < 8; ++t) { wv[t] = __expf(tv[t] - m); wsum += wv[t]; }
    float inv = 1.f / wsum;

    // park weights in dotsm[0..2047], j-index bit patterns in dotsm[2048..4095]
    #pragma unroll
    for (int t = 0; t < 8; ++t) {
        dotsm[(kk_r * 16 + ti_r) * 8 + t]        = wv[t] * inv;
        dotsm[2048 + (kk_r * 16 + ti_r) * 8 + t] = __int_as_float(tx[t]);
    }
    __syncthreads();

    // PV: thread = (ti_o, k2). arows[ti_o][k2*64+d] = sum_kk post[kk][k2] * sum_t w * v
    // arows (bf16, 16x1032 = 33024 B) reuses the q_c4/k_c4 region (34816 B).
    u16* arows = (u16*)fsm;
    const int ti_o = tid >> 4, k2 = tid & 15;
    {
        float acc[64];
        #pragma unroll
        for (int d = 0; d < 64; ++d) acc[d] = 0.f;
        const float* vws_base  = v_ws  + (size_t)(b * HS + k2) * NN * DH;
        const float* vmem_base = mem_v + (size_t)k2 * NM * DH;

        for (int kk = 0; kk < 16; ++kk) {
            float p2 = pp2[kk * 16 + k2];
            for (int t = 0; t < 8; ++t) {
                float w = dotsm[(kk * 16 + ti_o) * 8 + t] * p2;
                int j = __float_as_int(dotsm[2048 + (kk * 16 + ti_o) * 8 + t]);
                const float* vr = (j < NM) ? (vmem_base + (size_t)j * DH)
                                           : (vws_base + (size_t)(j - NM) * DH);
                #pragma unroll
                for (int r = 0; r < 16; ++r) {
                    float4 u = *(const float4*)&vr[r * 4];
                    acc[r * 4 + 0] += w * u.x; acc[r * 4 + 1] += w * u.y;
                    acc[r * 4 + 2] += w * u.z; acc[r * 4 + 3] += w * u.w;
                }
            }
        }
        #pragma unroll
        for (int d = 0; d < 64; ++d) {
            float o = acc[d];
            o = (o == o) ? o : 1e4f;             // V-side NaN sentinel (diagnostic)
            arows[ti_o * 1032 + k2 * 64 + d] = f2bf(o);
        }
    }
    __syncthreads();

    // fused out-projection: out_rows(16x1024) = arows(16x1024) @ Wo + bo  (f32 out)
    const int wave = tid >> 6, lane = tid & 63;
    const int ln16 = lane & 15, quad = lane >> 4;

    f32x4 oacc[16];
    #pragma unroll
    for (int t = 0; t < 16; ++t) {
        float bv = bo[(t * 4 + wave) * 16 + ln16];
        oacc[t][0] = bv; oacc[t][1] = bv; oacc[t][2] = bv; oacc[t][3] = bv;
    }

    for (int k0 = 0; k0 < 1024; k0 += 32) {
        bf16x8 af = *(const bf16x8*)&arows[ln16 * 1032 + k0 + quad * 8];
        #pragma unroll
        for (int t = 0; t < 16; ++t) {
            const int n = (t * 4 + wave) * 16 + ln16;
            u16 be[8];
            #pragma unroll
            for (int jj = 0; jj < 8; ++jj)
                be[jj] = f2bf(Wo[(size_t)(k0 + quad * 8 + jj) * 1024 + n]);
            bf16x8 bf_ = *(const bf16x8*)be;
            oacc[t] = __builtin_amdgcn_mfma_f32_16x16x32_bf16(af, bf_, oacc[t], 0, 0, 0);
        }
    }

    #pragma unroll
    for (int t = 0; t < 16; ++t) {
        const int n = (t * 4 + wave) * 16 + ln16;
        #pragma unroll
        for (int r = 0; r < 4; ++r) {
            int row = quad * 4 + r;
            out[(size_t)(b * NN + i0 + row) * DIM + n] = oacc[t][r];
        }
    }
}

// ---------------------------------------------------------------------------
extern "C" void kernel_launch(void* const* d_in, const int* in_sizes, int n_in,
                              void* d_out, int out_size, void* d_ws, size_t ws_size,
                              hipStream_t stream)
{
    (void)in_sizes; (void)n_in; (void)out_size; (void)ws_size;
    const float* x     = (const float*)d_in[0];
    const float* Wq    = (const float*)d_in[1];
    const float* Wk    = (const float*)d_in[2];
    const float* Wv    = (const float*)d_in[3];
    const float* pre   = (const float*)d_in[4];
    const float* post  = (const float*)d_in[5];
    const float* mem_k = (const float*)d_in[6];
    const float* mem_v = (const float*)d_in[7];
    const float* Wo    = (const float*)d_in[8];
    const float* bo    = (const float*)d_in[9];

    // workspace: K f32 [2][16][2048][64] + V f32 [2][16][2048][64] = 33.55 MB
    // (mem_k/mem_v rows are read directly from the f32 inputs in attn)
    float* k_ws = (float*)d_ws;
    float* v_ws = k_ws + (size_t)BB * HS * NN * DH;
    float* q_tmp = (float*)d_out;                            // Q f32 [b*n][1024]

    dim3 gg(32, 16);
    gemm_kernel<<<gg, 256, 0, stream>>>(x, Wq, q_tmp, nullptr, 1);  // Q -> d_out
    gemm_kernel<<<gg, 256, 0, stream>>>(x, Wk, k_ws, nullptr, 0);   // K -> ws (f32)
    gemm_kernel<<<gg, 256, 0, stream>>>(x, Wv, v_ws, nullptr, 0);   // V -> ws (f32)

    dim3 ga(128, 2);
    attn_kernel<<<ga, 256, 0, stream>>>(k_ws, v_ws, mem_k, mem_v,
                                        pre, post, Wo, bo, (float*)d_out);
}

// Round 8
// 1694.925 us; speedup vs baseline: 1.7330x; 1.7330x over previous
//
#include <hip/hip_runtime.h>
#include <hip/hip_bf16.h>

typedef unsigned short u16;
typedef unsigned int   u32;

#define BB   2
#define NN   2048
#define HS   16
#define DH   64
#define NM   16
#define JT   2064   // NM + NN
#define DIM  1024
#define CT   32     // j-tiles per chunk (512 keys)
#define JC   5      // max chunks: ceil(129/32)

__device__ __forceinline__ float bfval(u16 u) { return __uint_as_float(((u32)u) << 16); }
__device__ __forceinline__ u16 f2bf(float f)
{
    __hip_bfloat16 h = __float2bfloat16(f);
    return *(u16*)&h;
}

typedef __bf16 bf16x8 __attribute__((ext_vector_type(8)));
typedef float  f32x4  __attribute__((ext_vector_type(4)));

// ---------------------------------------------------------------------------
// Exact-f32 GEMM via 6-pass bf16 split MFMA (unchanged from R7, verified).
// mode 0: f32 scatter to [b][h][2048][64] head layout (K/V)
// mode 1: f32 row-major C = acc + bias (Q -> d_out)
// ---------------------------------------------------------------------------
__global__ __launch_bounds__(256) void gemm_kernel(
    const float* __restrict__ A, const float* __restrict__ Bw,
    float* __restrict__ dstf, const float* __restrict__ bias, int mode)
{
    __shared__ __align__(16) u16 a_h[128][32];
    __shared__ __align__(16) u16 a_m[128][32];
    __shared__ __align__(16) u16 a_l[128][32];
    __shared__ __align__(16) u16 b_hT[64][32];
    __shared__ __align__(16) u16 b_mT[64][32];
    __shared__ __align__(16) u16 b_lT[64][32];

    const int tid  = threadIdx.x;
    const int m0   = blockIdx.x * 128;
    const int n0   = blockIdx.y * 64;
    const int wave = tid >> 6, lane = tid & 63;
    const int ln16 = lane & 15, quad = lane >> 4;

    const int arow = tid >> 1;            // 0..127
    const int ac   = (tid & 1) * 16;      // 0 or 16
    const int brow = tid >> 3;            // 0..31
    const int bc   = (tid & 7) * 8;       // 0..56

    f32x4 acc[8] = {};

    for (int k0 = 0; k0 < 1024; k0 += 32) {
        float av[16];
        {
            const float4* ap = (const float4*)&A[(size_t)(m0 + arow) * 1024 + k0 + ac];
            *(float4*)&av[0]  = ap[0]; *(float4*)&av[4]  = ap[1];
            *(float4*)&av[8]  = ap[2]; *(float4*)&av[12] = ap[3];
        }
        float bv[8];
        {
            const float4* bp = (const float4*)&Bw[(size_t)(k0 + brow) * 1024 + n0 + bc];
            *(float4*)&bv[0] = bp[0]; *(float4*)&bv[4] = bp[1];
        }
        u16 ah[16], am[16], al[16], bh[8], bm[8], bl[8];
        #pragma unroll
        for (int e = 0; e < 16; ++e) {
            ah[e] = f2bf(av[e]);
            float d1 = av[e] - bfval(ah[e]);
            am[e] = f2bf(d1);
            al[e] = f2bf(d1 - bfval(am[e]));
        }
        #pragma unroll
        for (int e = 0; e < 8; ++e) {
            bh[e] = f2bf(bv[e]);
            float d1 = bv[e] - bfval(bh[e]);
            bm[e] = f2bf(d1);
            bl[e] = f2bf(d1 - bfval(bm[e]));
        }
        __syncthreads();
        *(uint4*)&a_h[arow][ac]     = ((uint4*)ah)[0];
        *(uint4*)&a_h[arow][ac + 8] = ((uint4*)ah)[1];
        *(uint4*)&a_m[arow][ac]     = ((uint4*)am)[0];
        *(uint4*)&a_m[arow][ac + 8] = ((uint4*)am)[1];
        *(uint4*)&a_l[arow][ac]     = ((uint4*)al)[0];
        *(uint4*)&a_l[arow][ac + 8] = ((uint4*)al)[1];
        #pragma unroll
        for (int e = 0; e < 8; ++e) {
            b_hT[bc + e][brow] = bh[e];
            b_mT[bc + e][brow] = bm[e];
            b_lT[bc + e][brow] = bl[e];
        }
        __syncthreads();

        bf16x8 a0h = *(const bf16x8*)&a_h[wave * 32 + ln16][quad * 8];
        bf16x8 a0m = *(const bf16x8*)&a_m[wave * 32 + ln16][quad * 8];
        bf16x8 a0l = *(const bf16x8*)&a_l[wave * 32 + ln16][quad * 8];
        bf16x8 a1h = *(const bf16x8*)&a_h[wave * 32 + 16 + ln16][quad * 8];
        bf16x8 a1m = *(const bf16x8*)&a_m[wave * 32 + 16 + ln16][quad * 8];
        bf16x8 a1l = *(const bf16x8*)&a_l[wave * 32 + 16 + ln16][quad * 8];
        #pragma unroll
        for (int c = 0; c < 4; ++c) {
            bf16x8 bh_ = *(const bf16x8*)&b_hT[c * 16 + ln16][quad * 8];
            bf16x8 bm_ = *(const bf16x8*)&b_mT[c * 16 + ln16][quad * 8];
            bf16x8 bl_ = *(const bf16x8*)&b_lT[c * 16 + ln16][quad * 8];
            acc[c]     = __builtin_amdgcn_mfma_f32_16x16x32_bf16(a0m, bm_, acc[c],     0, 0, 0);
            acc[c]     = __builtin_amdgcn_mfma_f32_16x16x32_bf16(a0h, bl_, acc[c],     0, 0, 0);
            acc[c]     = __builtin_amdgcn_mfma_f32_16x16x32_bf16(a0l, bh_, acc[c],     0, 0, 0);
            acc[c]     = __builtin_amdgcn_mfma_f32_16x16x32_bf16(a0h, bm_, acc[c],     0, 0, 0);
            acc[c]     = __builtin_amdgcn_mfma_f32_16x16x32_bf16(a0m, bh_, acc[c],     0, 0, 0);
            acc[c]     = __builtin_amdgcn_mfma_f32_16x16x32_bf16(a0h, bh_, acc[c],     0, 0, 0);
            acc[4 + c] = __builtin_amdgcn_mfma_f32_16x16x32_bf16(a1m, bm_, acc[4 + c], 0, 0, 0);
            acc[4 + c] = __builtin_amdgcn_mfma_f32_16x16x32_bf16(a1h, bl_, acc[4 + c], 0, 0, 0);
            acc[4 + c] = __builtin_amdgcn_mfma_f32_16x16x32_bf16(a1l, bh_, acc[4 + c], 0, 0, 0);
            acc[4 + c] = __builtin_amdgcn_mfma_f32_16x16x32_bf16(a1h, bm_, acc[4 + c], 0, 0, 0);
            acc[4 + c] = __builtin_amdgcn_mfma_f32_16x16x32_bf16(a1m, bh_, acc[4 + c], 0, 0, 0);
            acc[4 + c] = __builtin_amdgcn_mfma_f32_16x16x32_bf16(a1h, bh_, acc[4 + c], 0, 0, 0);
        }
    }

    #pragma unroll
    for (int hf = 0; hf < 2; ++hf) {
        #pragma unroll
        for (int c = 0; c < 4; ++c) {
            #pragma unroll
            for (int r = 0; r < 4; ++r) {
                int row = m0 + wave * 32 + hf * 16 + quad * 4 + r;
                int col = n0 + c * 16 + ln16;
                float v = acc[hf * 4 + c][r];
                if (mode == 1) {
                    if (bias) v += bias[col];
                    dstf[(size_t)row * 1024 + col] = v;
                } else {
                    int b = row >> 11, i = row & 2047;
                    int h = col >> 6, d = col & 63;
                    dstf[(((size_t)(b * HS + h)) * NN + i) * DH + d] = v;
                }
            }
        }
    }
}

// ---------------------------------------------------------------------------
// Phase 1: scores + partial top-8 per j-chunk.
// grid (jc, i-tile, b). Chunk jc owns tiles [jc*CT, min(jc*CT+CT, ntiles)).
// Inner machinery identical to R7's verified attn loop; partial top-8
// (sorted desc) written to ws_val/ws_idx[b][kk][i][jc][8].
// ---------------------------------------------------------------------------
__global__ __launch_bounds__(256) void score_topk_kernel(
    const float* __restrict__ k_ws, const float* __restrict__ mem_k,
    const float* __restrict__ q_all, const float* __restrict__ pre,
    float* __restrict__ ws_val, int* __restrict__ ws_idx)
{
    const int jc = blockIdx.x;
    const int iy = blockIdx.y;
    const int b  = blockIdx.z;
    const int ntiles = iy + 2;
    const int jt_lo = jc * CT;
    if (jt_lo >= ntiles) return;                 // block-uniform early exit
    const int jt_hi = min(jt_lo + CT, ntiles);

    __shared__ __align__(16) float fsm[13312];
    float* q_c4  = fsm;            // [4][16][68] f32
    float* k_c4  = fsm + 4352;     // [4][16][68] f32
    float* dotsm = fsm + 8704;     // [4096] mixed scores [kk][ti][tj]
    float* pp    = fsm + 12800;    // [256] pre_proj

    const int tid = threadIdx.x;
    const int i0  = iy * 16;

    pp[tid] = pre[tid];

    const float* qsrc = q_all + (size_t)(b * NN + i0) * DIM;

    const int ti = tid >> 4, tj = tid & 15;
    const int kk_r = tid & 15, ti_r = tid >> 4;

    float tv[8];
    int   tx[8];
    #pragma unroll
    for (int t = 0; t < 8; ++t) { tv[t] = -1e30f; tx[t] = 0; }
    const int jlim = NM + i0 + ti_r;

    for (int jt = jt_lo; jt < jt_hi; ++jt) {
        #pragma unroll
        for (int kk = 0; kk < 16; ++kk) dotsm[kk * 256 + ti * 16 + tj] = 0.f;

        for (int c4 = 0; c4 < 4; ++c4) {
            __syncthreads();
            #pragma unroll
            for (int p = 0; p < 4; ++p) {
                int f = tid + p * 256;
                int row = f >> 4;
                int c4i = f & 15;
                int hh = row >> 4, r = row & 15;
                float4 qa = *(const float4*)&qsrc[(size_t)r * DIM + (c4 * 4 + hh) * 64 + c4i * 4];
                *(float4*)&q_c4[row * 68 + c4i * 4] = qa;
                float4 ka;
                if (jt == 0)
                    ka = *(const float4*)&mem_k[((c4 * 4 + hh) * NM + r) * DH + c4i * 4];
                else
                    ka = *(const float4*)
                        &k_ws[((size_t)(b * HS + c4 * 4 + hh) * NN + (jt - 1) * 16 + r) * DH + c4i * 4];
                *(float4*)&k_c4[row * 68 + c4i * 4] = ka;
            }
            __syncthreads();

            float part[16];
            #pragma unroll
            for (int kk = 0; kk < 16; ++kk) part[kk] = 0.f;
            for (int hh = 0; hh < 4; ++hh) {
                const float* qr = &q_c4[(hh * 16 + ti) * 68];
                const float* kr = &k_c4[(hh * 16 + tj) * 68];
                float d0 = 0.f, d1 = 0.f, d2 = 0.f, d3 = 0.f;   // 4-way ILP chain split
                #pragma unroll
                for (int d = 0; d < 64; d += 4) {
                    d0 += qr[d]     * kr[d];
                    d1 += qr[d + 1] * kr[d + 1];
                    d2 += qr[d + 2] * kr[d + 2];
                    d3 += qr[d + 3] * kr[d + 3];
                }
                float dot = ((d0 + d1) + (d2 + d3)) * 0.125f;
                dot = (dot == dot) ? dot : -1e30f;
                const int h = c4 * 4 + hh;
                #pragma unroll
                for (int kk = 0; kk < 16; ++kk) part[kk] += pp[h * 16 + kk] * dot;
            }
            #pragma unroll
            for (int kk = 0; kk < 16; ++kk) dotsm[kk * 256 + ti * 16 + tj] += part[kk];
        }
        __syncthreads();

        for (int s = 0; s < 16; ++s) {
            int tjj = (s + kk_r) & 15;
            int j = jt * 16 + tjj;
            if (j <= jlim) {
                float c = dotsm[kk_r * 256 + ti_r * 16 + tjj];
                if (c > tv[7]) {
                    #pragma unroll
                    for (int t = 7; t >= 1; --t) {
                        if (c > tv[t - 1])      { tv[t] = tv[t - 1]; tx[t] = tx[t - 1]; }
                        else if (c > tv[t])     { tv[t] = c;         tx[t] = j; }
                    }
                    if (c > tv[0]) { tv[0] = c; tx[0] = j; }
                }
            }
        }
        __syncthreads();
    }

    size_t base = ((((size_t)b * HS + kk_r) * NN + i0 + ti_r) * JC + jc) * 8;
    #pragma unroll
    for (int t = 0; t < 8; ++t) {
        ws_val[base + t] = tv[t];
        ws_idx[base + t] = tx[t];
    }
}

// ---------------------------------------------------------------------------
// Phase 2: merge partial top-8s -> softmax -> sparse PV -> fused out-proj.
// One block per (b, 16-query rows). PV/out-proj verbatim from R7 (verified).
// ---------------------------------------------------------------------------
__global__ __launch_bounds__(256) void merge_pv_kernel(
    const float* __restrict__ v_ws, const float* __restrict__ mem_v,
    const float* __restrict__ ws_val, const int* __restrict__ ws_idx,
    const float* __restrict__ post, const float* __restrict__ Wo,
    const float* __restrict__ bo, float* __restrict__ out)
{
    __shared__ __align__(16) float fsm[13312];
    float* dotsm = fsm + 8704;     // [4096]: w park [0..2047], j park [2048..4095]
    float* pp2   = fsm + 13056;    // [256] post_proj
    u16*   arows = (u16*)fsm;      // [16][1032] bf16 (PV rows), fits in fsm[0..8704)

    const int tid = threadIdx.x;
    const int b   = blockIdx.y;
    const int i0  = blockIdx.x * 16;
    const int ntiles = blockIdx.x + 2;
    const int jc_cnt = (ntiles + CT - 1) / CT;

    pp2[tid] = post[tid];

    const int kk_r = tid & 15, ti_r = tid >> 4;

    // merge partial top-8s (each sorted desc; same insertion machinery)
    float tv[8];
    int   tx[8];
    #pragma unroll
    for (int t = 0; t < 8; ++t) { tv[t] = -1e30f; tx[t] = 0; }

    size_t rbase = (((size_t)b * HS + kk_r) * NN + i0 + ti_r) * JC;
    for (int jc = 0; jc < jc_cnt; ++jc) {
        #pragma unroll
        for (int t2 = 0; t2 < 8; ++t2) {
            float c = ws_val[(rbase + jc) * 8 + t2];
            int   j = ws_idx[(rbase + jc) * 8 + t2];
            if (c > tv[7]) {
                #pragma unroll
                for (int t = 7; t >= 1; --t) {
                    if (c > tv[t - 1])      { tv[t] = tv[t - 1]; tx[t] = tx[t - 1]; }
                    else if (c > tv[t])     { tv[t] = c;         tx[t] = j; }
                }
                if (c > tv[0]) { tv[0] = c; tx[0] = j; }
            }
        }
    }

    // sparse softmax over the kept 8
    float m = tv[0];
    float wv[8], wsum = 0.f;
    #pragma unroll
    for (int t = 0; t < 8; ++t) { wv[t] = __expf(tv[t] - m); wsum += wv[t]; }
    float inv = 1.f / wsum;

    #pragma unroll
    for (int t = 0; t < 8; ++t) {
        dotsm[(kk_r * 16 + ti_r) * 8 + t]        = wv[t] * inv;
        dotsm[2048 + (kk_r * 16 + ti_r) * 8 + t] = __int_as_float(tx[t]);
    }
    __syncthreads();

    // PV: thread = (ti_o, k2)
    const int ti_o = tid >> 4, k2 = tid & 15;
    {
        float acc[64];
        #pragma unroll
        for (int d = 0; d < 64; ++d) acc[d] = 0.f;
        const float* vws_base  = v_ws  + (size_t)(b * HS + k2) * NN * DH;
        const float* vmem_base = mem_v + (size_t)k2 * NM * DH;

        for (int kk = 0; kk < 16; ++kk) {
            float p2 = pp2[kk * 16 + k2];
            for (int t = 0; t < 8; ++t) {
                float w = dotsm[(kk * 16 + ti_o) * 8 + t] * p2;
                int j = __float_as_int(dotsm[2048 + (kk * 16 + ti_o) * 8 + t]);
                const float* vr = (j < NM) ? (vmem_base + (size_t)j * DH)
                                           : (vws_base + (size_t)(j - NM) * DH);
                #pragma unroll
                for (int r = 0; r < 16; ++r) {
                    float4 u = *(const float4*)&vr[r * 4];
                    acc[r * 4 + 0] += w * u.x; acc[r * 4 + 1] += w * u.y;
                    acc[r * 4 + 2] += w * u.z; acc[r * 4 + 3] += w * u.w;
                }
            }
        }
        #pragma unroll
        for (int d = 0; d < 64; ++d) {
            float o = acc[d];
            o = (o == o) ? o : 1e4f;             // V-side NaN sentinel (diagnostic)
            arows[ti_o * 1032 + k2 * 64 + d] = f2bf(o);
        }
    }
    __syncthreads();

    // fused out-projection: out_rows(16x1024) = arows(16x1024) @ Wo + bo
    const int wave = tid >> 6, lane = tid & 63;
    const int ln16 = lane & 15, quad = lane >> 4;

    f32x4 oacc[16];
    #pragma unroll
    for (int t = 0; t < 16; ++t) {
        float bv = bo[(t * 4 + wave) * 16 + ln16];
        oacc[t][0] = bv; oacc[t][1] = bv; oacc[t][2] = bv; oacc[t][3] = bv;
    }

    for (int k0 = 0; k0 < 1024; k0 += 32) {
        bf16x8 af = *(const bf16x8*)&arows[ln16 * 1032 + k0 + quad * 8];
        #pragma unroll
        for (int t = 0; t < 16; ++t) {
            const int n = (t * 4 + wave) * 16 + ln16;
            u16 be[8];
            #pragma unroll
            for (int jj = 0; jj < 8; ++jj)
                be[jj] = f2bf(Wo[(size_t)(k0 + quad * 8 + jj) * 1024 + n]);
            bf16x8 bf_ = *(const bf16x8*)be;
            oacc[t] = __builtin_amdgcn_mfma_f32_16x16x32_bf16(af, bf_, oacc[t], 0, 0, 0);
        }
    }

    #pragma unroll
    for (int t = 0; t < 16; ++t) {
        const int n = (t * 4 + wave) * 16 + ln16;
        #pragma unroll
        for (int r = 0; r < 4; ++r) {
            int row = quad * 4 + r;
            out[(size_t)(b * NN + i0 + row) * DIM + n] = oacc[t][r];
        }
    }
}

// ---------------------------------------------------------------------------
extern "C" void kernel_launch(void* const* d_in, const int* in_sizes, int n_in,
                              void* d_out, int out_size, void* d_ws, size_t ws_size,
                              hipStream_t stream)
{
    (void)in_sizes; (void)n_in; (void)out_size; (void)ws_size;
    const float* x     = (const float*)d_in[0];
    const float* Wq    = (const float*)d_in[1];
    const float* Wk    = (const float*)d_in[2];
    const float* Wv    = (const float*)d_in[3];
    const float* pre   = (const float*)d_in[4];
    const float* post  = (const float*)d_in[5];
    const float* mem_k = (const float*)d_in[6];
    const float* mem_v = (const float*)d_in[7];
    const float* Wo    = (const float*)d_in[8];
    const float* bo    = (const float*)d_in[9];

    // workspace: K f32 16.78 MB + V f32 16.78 MB + partial top-8
    // (val f32 + idx i32, [2][16][2048][JC][8]) 21.0 MB = 54.6 MB total
    float* k_ws   = (float*)d_ws;
    float* v_ws   = k_ws + (size_t)BB * HS * NN * DH;
    float* ws_val = v_ws + (size_t)BB * HS * NN * DH;
    int*   ws_idx = (int*)(ws_val + (size_t)BB * HS * NN * JC * 8);
    float* q_tmp  = (float*)d_out;                           // Q f32 [b*n][1024]

    dim3 gg(32, 16);
    gemm_kernel<<<gg, 256, 0, stream>>>(x, Wq, q_tmp, nullptr, 1);  // Q -> d_out
    gemm_kernel<<<gg, 256, 0, stream>>>(x, Wk, k_ws, nullptr, 0);   // K -> ws (f32)
    gemm_kernel<<<gg, 256, 0, stream>>>(x, Wv, v_ws, nullptr, 0);   // V -> ws (f32)

    dim3 gs(JC, 128, 2);
    score_topk_kernel<<<gs, 256, 0, stream>>>(k_ws, mem_k, (const float*)d_out,
                                              pre, ws_val, ws_idx);

    dim3 ga(128, 2);
    merge_pv_kernel<<<ga, 256, 0, stream>>>(v_ws, mem_v, ws_val, ws_idx,
                                            post, Wo, bo, (float*)d_out);
}

// Round 9
// 1348.301 us; speedup vs baseline: 2.1786x; 1.2571x over previous
//
#include <hip/hip_runtime.h>
#include <hip/hip_bf16.h>

typedef unsigned short u16;
typedef unsigned int   u32;

#define BB   2
#define NN   2048
#define HS   16
#define DH   64
#define NM   16
#define JT   2064   // NM + NN
#define DIM  1024
#define CT   48     // j-tiles per chunk (768 keys)
#define JC   3      // ceil(129/48)

#define SPLITSZ ((size_t)BB * HS * JT * DH)   // elements per K-split plane

__device__ __forceinline__ float bfval(u16 u) { return __uint_as_float(((u32)u) << 16); }
__device__ __forceinline__ u16 f2bf(float f)
{
    __hip_bfloat16 h = __float2bfloat16(f);
    return *(u16*)&h;
}

typedef __bf16 bf16x8 __attribute__((ext_vector_type(8)));
typedef float  f32x4  __attribute__((ext_vector_type(4)));

// ---------------------------------------------------------------------------
// mem_k rows -> K-split planes (hi/mid/lo bf16) at key rows 0..15.
// ---------------------------------------------------------------------------
__global__ void prep_mem_kernel(const float* __restrict__ mem_k, u16* __restrict__ k_sp)
{
    int t = blockIdx.x * 256 + threadIdx.x;          // 0 .. 32767
    int d = t & 63, j = (t >> 6) & 15, h = (t >> 10) & 15, b = (t >> 14) & 1;
    float x = mem_k[(h * NM + j) * DH + d];
    size_t di = ((size_t)(b * HS + h) * JT + j) * DH + d;
    u16 sh = f2bf(x);
    float d1 = x - bfval(sh);
    u16 sm = f2bf(d1);
    u16 sl = f2bf(d1 - bfval(sm));
    k_sp[di] = sh; k_sp[di + SPLITSZ] = sm; k_sp[di + 2 * SPLITSZ] = sl;
}

// ---------------------------------------------------------------------------
// Exact-f32 GEMM via 6-pass bf16 split MFMA (core verified R7/R8).
// mode 0: f32 scatter to [b][h][2048][64] head layout (V)
// mode 1: f32 row-major C = acc (Q -> d_out)
// mode 2: K: split into hi/mid/lo bf16 planes, scatter [b][h][NM+i][64]
// ---------------------------------------------------------------------------
__global__ __launch_bounds__(256) void gemm_kernel(
    const float* __restrict__ A, const float* __restrict__ Bw,
    u16* __restrict__ dst16, float* __restrict__ dstf, int mode)
{
    __shared__ __align__(16) u16 a_h[128][32];
    __shared__ __align__(16) u16 a_m[128][32];
    __shared__ __align__(16) u16 a_l[128][32];
    __shared__ __align__(16) u16 b_hT[64][32];
    __shared__ __align__(16) u16 b_mT[64][32];
    __shared__ __align__(16) u16 b_lT[64][32];

    const int tid  = threadIdx.x;
    const int m0   = blockIdx.x * 128;
    const int n0   = blockIdx.y * 64;
    const int wave = tid >> 6, lane = tid & 63;
    const int ln16 = lane & 15, quad = lane >> 4;

    const int arow = tid >> 1;            // 0..127
    const int ac   = (tid & 1) * 16;      // 0 or 16
    const int brow = tid >> 3;            // 0..31
    const int bc   = (tid & 7) * 8;       // 0..56

    f32x4 acc[8] = {};

    for (int k0 = 0; k0 < 1024; k0 += 32) {
        float av[16];
        {
            const float4* ap = (const float4*)&A[(size_t)(m0 + arow) * 1024 + k0 + ac];
            *(float4*)&av[0]  = ap[0]; *(float4*)&av[4]  = ap[1];
            *(float4*)&av[8]  = ap[2]; *(float4*)&av[12] = ap[3];
        }
        float bv[8];
        {
            const float4* bp = (const float4*)&Bw[(size_t)(k0 + brow) * 1024 + n0 + bc];
            *(float4*)&bv[0] = bp[0]; *(float4*)&bv[4] = bp[1];
        }
        u16 ah[16], am[16], al[16], bh[8], bm[8], bl[8];
        #pragma unroll
        for (int e = 0; e < 16; ++e) {
            ah[e] = f2bf(av[e]);
            float d1 = av[e] - bfval(ah[e]);
            am[e] = f2bf(d1);
            al[e] = f2bf(d1 - bfval(am[e]));
        }
        #pragma unroll
        for (int e = 0; e < 8; ++e) {
            bh[e] = f2bf(bv[e]);
            float d1 = bv[e] - bfval(bh[e]);
            bm[e] = f2bf(d1);
            bl[e] = f2bf(d1 - bfval(bm[e]));
        }
        __syncthreads();
        *(uint4*)&a_h[arow][ac]     = ((uint4*)ah)[0];
        *(uint4*)&a_h[arow][ac + 8] = ((uint4*)ah)[1];
        *(uint4*)&a_m[arow][ac]     = ((uint4*)am)[0];
        *(uint4*)&a_m[arow][ac + 8] = ((uint4*)am)[1];
        *(uint4*)&a_l[arow][ac]     = ((uint4*)al)[0];
        *(uint4*)&a_l[arow][ac + 8] = ((uint4*)al)[1];
        #pragma unroll
        for (int e = 0; e < 8; ++e) {
            b_hT[bc + e][brow] = bh[e];
            b_mT[bc + e][brow] = bm[e];
            b_lT[bc + e][brow] = bl[e];
        }
        __syncthreads();

        bf16x8 a0h = *(const bf16x8*)&a_h[wave * 32 + ln16][quad * 8];
        bf16x8 a0m = *(const bf16x8*)&a_m[wave * 32 + ln16][quad * 8];
        bf16x8 a0l = *(const bf16x8*)&a_l[wave * 32 + ln16][quad * 8];
        bf16x8 a1h = *(const bf16x8*)&a_h[wave * 32 + 16 + ln16][quad * 8];
        bf16x8 a1m = *(const bf16x8*)&a_m[wave * 32 + 16 + ln16][quad * 8];
        bf16x8 a1l = *(const bf16x8*)&a_l[wave * 32 + 16 + ln16][quad * 8];
        #pragma unroll
        for (int c = 0; c < 4; ++c) {
            bf16x8 bh_ = *(const bf16x8*)&b_hT[c * 16 + ln16][quad * 8];
            bf16x8 bm_ = *(const bf16x8*)&b_mT[c * 16 + ln16][quad * 8];
            bf16x8 bl_ = *(const bf16x8*)&b_lT[c * 16 + ln16][quad * 8];
            acc[c]     = __builtin_amdgcn_mfma_f32_16x16x32_bf16(a0m, bm_, acc[c],     0, 0, 0);
            acc[c]     = __builtin_amdgcn_mfma_f32_16x16x32_bf16(a0h, bl_, acc[c],     0, 0, 0);
            acc[c]     = __builtin_amdgcn_mfma_f32_16x16x32_bf16(a0l, bh_, acc[c],     0, 0, 0);
            acc[c]     = __builtin_amdgcn_mfma_f32_16x16x32_bf16(a0h, bm_, acc[c],     0, 0, 0);
            acc[c]     = __builtin_amdgcn_mfma_f32_16x16x32_bf16(a0m, bh_, acc[c],     0, 0, 0);
            acc[c]     = __builtin_amdgcn_mfma_f32_16x16x32_bf16(a0h, bh_, acc[c],     0, 0, 0);
            acc[4 + c] = __builtin_amdgcn_mfma_f32_16x16x32_bf16(a1m, bm_, acc[4 + c], 0, 0, 0);
            acc[4 + c] = __builtin_amdgcn_mfma_f32_16x16x32_bf16(a1h, bl_, acc[4 + c], 0, 0, 0);
            acc[4 + c] = __builtin_amdgcn_mfma_f32_16x16x32_bf16(a1l, bh_, acc[4 + c], 0, 0, 0);
            acc[4 + c] = __builtin_amdgcn_mfma_f32_16x16x32_bf16(a1h, bm_, acc[4 + c], 0, 0, 0);
            acc[4 + c] = __builtin_amdgcn_mfma_f32_16x16x32_bf16(a1m, bh_, acc[4 + c], 0, 0, 0);
            acc[4 + c] = __builtin_amdgcn_mfma_f32_16x16x32_bf16(a1h, bh_, acc[4 + c], 0, 0, 0);
        }
    }

    #pragma unroll
    for (int hf = 0; hf < 2; ++hf) {
        #pragma unroll
        for (int c = 0; c < 4; ++c) {
            #pragma unroll
            for (int r = 0; r < 4; ++r) {
                int row = m0 + wave * 32 + hf * 16 + quad * 4 + r;
                int col = n0 + c * 16 + ln16;
                float v = acc[hf * 4 + c][r];
                if (mode == 1) {
                    dstf[(size_t)row * 1024 + col] = v;
                } else {
                    int b = row >> 11, i = row & 2047;
                    int hd = col >> 6, d = col & 63;
                    if (mode == 0) {
                        dstf[(((size_t)(b * HS + hd)) * NN + i) * DH + d] = v;
                    } else {
                        size_t di = (((size_t)(b * HS + hd)) * JT + NM + i) * DH + d;
                        u16 sh = f2bf(v);
                        float d1 = v - bfval(sh);
                        u16 sm = f2bf(d1);
                        u16 sl = f2bf(d1 - bfval(sm));
                        dst16[di] = sh;
                        dst16[di + SPLITSZ] = sm;
                        dst16[di + 2 * SPLITSZ] = sl;
                    }
                }
            }
        }
    }
}

// ---------------------------------------------------------------------------
// Phase 1 (MFMA): scores + partial top-8 per j-chunk.
// grid (jc, i-tile, b). Each wave owns 4 heads. Q A-frags (6-split) in VGPRs
// loaded once per block; K B-frags read directly from global split planes
// (native B layout). Per tile: 48 MFMA/wave -> S in LDS -> VALU pre_proj mix
// -> register top-8 (machinery unchanged from R8, verified).
// ---------------------------------------------------------------------------
__global__ __launch_bounds__(256) void score_topk_kernel(
    const u16* __restrict__ k_sp, const float* __restrict__ q_all,
    const float* __restrict__ pre,
    float* __restrict__ ws_val, int* __restrict__ ws_idx)
{
    const int jc = blockIdx.x;
    const int iy = blockIdx.y;
    const int b  = blockIdx.z;
    const int ntiles = iy + 2;
    const int jt_lo = jc * CT;
    if (jt_lo >= ntiles) return;                 // block-uniform early exit
    const int jt_hi = min(jt_lo + CT, ntiles);

    __shared__ __align__(16) float fsm[8448];
    float* S  = fsm;            // [16][256]  MFMA C-layout scores per head
    float* MX = fsm + 4096;     // [16][256]  mixed scores [kk][ti*16+tj]
    float* pp = fsm + 8192;     // [256] pre_proj * 0.125

    const int tid  = threadIdx.x;
    const int i0   = iy * 16;
    const int wave = tid >> 6, lane = tid & 63;
    const int ln16 = lane & 15, quad = lane >> 4;

    pp[tid] = pre[tid] * 0.125f;

    // Q A-frags: 4 heads/wave x 2 K-halves x 3 splits, loaded once per block.
    bf16x8 qh[4][2], qm[4][2], ql[4][2];
    {
        const float* qrow = q_all + (size_t)(b * NN + i0 + ln16) * DIM;
        #pragma unroll
        for (int h4 = 0; h4 < 4; ++h4) {
            const int h = wave * 4 + h4;
            #pragma unroll
            for (int half = 0; half < 2; ++half) {
                const float* src = qrow + h * 64 + half * 32 + quad * 8;
                float4 u0 = *(const float4*)src;
                float4 u1 = *(const float4*)(src + 4);
                float xv[8] = {u0.x, u0.y, u0.z, u0.w, u1.x, u1.y, u1.z, u1.w};
                u16 eh[8], em[8], el[8];
                #pragma unroll
                for (int e = 0; e < 8; ++e) {
                    eh[e] = f2bf(xv[e]);
                    float d1 = xv[e] - bfval(eh[e]);
                    em[e] = f2bf(d1);
                    el[e] = f2bf(d1 - bfval(em[e]));
                }
                qh[h4][half] = *(bf16x8*)eh;
                qm[h4][half] = *(bf16x8*)em;
                ql[h4][half] = *(bf16x8*)el;
            }
        }
    }

    const int kk_r = tid & 15, ti_r = tid >> 4;
    float tv[8];
    int   tx[8];
    #pragma unroll
    for (int t = 0; t < 8; ++t) { tv[t] = -1e30f; tx[t] = 0; }
    const int jlim = NM + i0 + ti_r;

    for (int jt = jt_lo; jt < jt_hi; ++jt) {
        // scores via MFMA: wave w computes heads 4w..4w+3
        #pragma unroll
        for (int h4 = 0; h4 < 4; ++h4) {
            const int h = wave * 4 + h4;
            const u16* kb = k_sp + ((size_t)(b * HS + h) * JT + jt * 16 + ln16) * DH;
            f32x4 acc = {};
            #pragma unroll
            for (int half = 0; half < 2; ++half) {
                const u16* k0 = kb + half * 32 + quad * 8;
                bf16x8 kh_ = *(const bf16x8*)(k0);
                bf16x8 km_ = *(const bf16x8*)(k0 + SPLITSZ);
                bf16x8 kl_ = *(const bf16x8*)(k0 + 2 * SPLITSZ);
                acc = __builtin_amdgcn_mfma_f32_16x16x32_bf16(qm[h4][half], km_, acc, 0, 0, 0);
                acc = __builtin_amdgcn_mfma_f32_16x16x32_bf16(qh[h4][half], kl_, acc, 0, 0, 0);
                acc = __builtin_amdgcn_mfma_f32_16x16x32_bf16(ql[h4][half], kh_, acc, 0, 0, 0);
                acc = __builtin_amdgcn_mfma_f32_16x16x32_bf16(qh[h4][half], km_, acc, 0, 0, 0);
                acc = __builtin_amdgcn_mfma_f32_16x16x32_bf16(qm[h4][half], kh_, acc, 0, 0, 0);
                acc = __builtin_amdgcn_mfma_f32_16x16x32_bf16(qh[h4][half], kh_, acc, 0, 0, 0);
            }
            // C-layout: row(ti) = quad*4+reg, col(tj=key) = ln16
            #pragma unroll
            for (int r = 0; r < 4; ++r)
                S[h * 256 + (quad * 4 + r) * 16 + ln16] = acc[r];
        }
        __syncthreads();

        // head mix: cell = tid (= ti*16+tj); MX[kk][cell] = sum_h pp[h][kk]*S[h][cell]
        {
            float sv[16];
            #pragma unroll
            for (int h = 0; h < 16; ++h) sv[h] = S[h * 256 + tid];
            #pragma unroll
            for (int kk = 0; kk < 16; ++kk) {
                float mx = 0.f;
                #pragma unroll
                for (int h = 0; h < 16; ++h) mx += pp[h * 16 + kk] * sv[h];
                MX[kk * 256 + tid] = mx;
            }
        }
        __syncthreads();

        // top-8 update for row (kk_r, ti_r); rotate tj start by kk_r
        for (int s = 0; s < 16; ++s) {
            int tjj = (s + kk_r) & 15;
            int j = jt * 16 + tjj;
            if (j <= jlim) {
                float c = MX[kk_r * 256 + ti_r * 16 + tjj];
                if (c > tv[7]) {
                    #pragma unroll
                    for (int t = 7; t >= 1; --t) {
                        if (c > tv[t - 1])      { tv[t] = tv[t - 1]; tx[t] = tx[t - 1]; }
                        else if (c > tv[t])     { tv[t] = c;         tx[t] = j; }
                    }
                    if (c > tv[0]) { tv[0] = c; tx[0] = j; }
                }
            }
        }
        __syncthreads();
    }

    size_t base = ((((size_t)b * HS + kk_r) * NN + i0 + ti_r) * JC + jc) * 8;
    #pragma unroll
    for (int t = 0; t < 8; ++t) {
        ws_val[base + t] = tv[t];
        ws_idx[base + t] = tx[t];
    }
}

// ---------------------------------------------------------------------------
// Phase 2: merge partial top-8s -> softmax -> sparse PV -> fused out-proj.
// One block per (b, 16-query rows). Verbatim from R8 (verified), JC=3.
// ---------------------------------------------------------------------------
__global__ __launch_bounds__(256) void merge_pv_kernel(
    const float* __restrict__ v_ws, const float* __restrict__ mem_v,
    const float* __restrict__ ws_val, const int* __restrict__ ws_idx,
    const float* __restrict__ post, const float* __restrict__ Wo,
    const float* __restrict__ bo, float* __restrict__ out)
{
    __shared__ __align__(16) float fsm[13312];
    float* dotsm = fsm + 8704;     // [4096]: w park [0..2047], j park [2048..4095]
    float* pp2   = fsm + 13056;    // [256] post_proj
    u16*   arows = (u16*)fsm;      // [16][1032] bf16 (PV rows)

    const int tid = threadIdx.x;
    const int b   = blockIdx.y;
    const int i0  = blockIdx.x * 16;
    const int ntiles = blockIdx.x + 2;
    const int jc_cnt = (ntiles + CT - 1) / CT;

    pp2[tid] = post[tid];

    const int kk_r = tid & 15, ti_r = tid >> 4;

    float tv[8];
    int   tx[8];
    #pragma unroll
    for (int t = 0; t < 8; ++t) { tv[t] = -1e30f; tx[t] = 0; }

    size_t rbase = (((size_t)b * HS + kk_r) * NN + i0 + ti_r) * JC;
    for (int jc = 0; jc < jc_cnt; ++jc) {
        #pragma unroll
        for (int t2 = 0; t2 < 8; ++t2) {
            float c = ws_val[(rbase + jc) * 8 + t2];
            int   j = ws_idx[(rbase + jc) * 8 + t2];
            if (c > tv[7]) {
                #pragma unroll
                for (int t = 7; t >= 1; --t) {
                    if (c > tv[t - 1])      { tv[t] = tv[t - 1]; tx[t] = tx[t - 1]; }
                    else if (c > tv[t])     { tv[t] = c;         tx[t] = j; }
                }
                if (c > tv[0]) { tv[0] = c; tx[0] = j; }
            }
        }
    }

    float m = tv[0];
    float wv[8], wsum = 0.f;
    #pragma unroll
    for (int t = 0; t < 8; ++t) { wv[t] = __expf(tv[t] - m); wsum += wv[t]; }
    float inv = 1.f / wsum;

    #pragma unroll
    for (int t = 0; t < 8; ++t) {
        dotsm[(kk_r * 16 + ti_r) * 8 + t]        = wv[t] * inv;
        dotsm[2048 + (kk_r * 16 + ti_r) * 8 + t] = __int_as_float(tx[t]);
    }
    __syncthreads();

    // PV: thread = (ti_o, k2)
    const int ti_o = tid >> 4, k2 = tid & 15;
    {
        float acc[64];
        #pragma unroll
        for (int d = 0; d < 64; ++d) acc[d] = 0.f;
        const float* vws_base  = v_ws  + (size_t)(b * HS + k2) * NN * DH;
        const float* vmem_base = mem_v + (size_t)k2 * NM * DH;

        for (int kk = 0; kk < 16; ++kk) {
            float p2 = pp2[kk * 16 + k2];
            for (int t = 0; t < 8; ++t) {
                float w = dotsm[(kk * 16 + ti_o) * 8 + t] * p2;
                int j = __float_as_int(dotsm[2048 + (kk * 16 + ti_o) * 8 + t]);
                const float* vr = (j < NM) ? (vmem_base + (size_t)j * DH)
                                           : (vws_base + (size_t)(j - NM) * DH);
                #pragma unroll
                for (int r = 0; r < 16; ++r) {
                    float4 u = *(const float4*)&vr[r * 4];
                    acc[r * 4 + 0] += w * u.x; acc[r * 4 + 1] += w * u.y;
                    acc[r * 4 + 2] += w * u.z; acc[r * 4 + 3] += w * u.w;
                }
            }
        }
        #pragma unroll
        for (int d = 0; d < 64; ++d) {
            float o = acc[d];
            o = (o == o) ? o : 1e4f;             // V-side NaN sentinel (diagnostic)
            arows[ti_o * 1032 + k2 * 64 + d] = f2bf(o);
        }
    }
    __syncthreads();

    // fused out-projection: out_rows(16x1024) = arows(16x1024) @ Wo + bo
    const int wave = tid >> 6, lane = tid & 63;
    const int ln16 = lane & 15, quad = lane >> 4;

    f32x4 oacc[16];
    #pragma unroll
    for (int t = 0; t < 16; ++t) {
        float bv = bo[(t * 4 + wave) * 16 + ln16];
        oacc[t][0] = bv; oacc[t][1] = bv; oacc[t][2] = bv; oacc[t][3] = bv;
    }

    for (int k0 = 0; k0 < 1024; k0 += 32) {
        bf16x8 af = *(const bf16x8*)&arows[ln16 * 1032 + k0 + quad * 8];
        #pragma unroll
        for (int t = 0; t < 16; ++t) {
            const int n = (t * 4 + wave) * 16 + ln16;
            u16 be[8];
            #pragma unroll
            for (int jj = 0; jj < 8; ++jj)
                be[jj] = f2bf(Wo[(size_t)(k0 + quad * 8 + jj) * 1024 + n]);
            bf16x8 bf_ = *(const bf16x8*)be;
            oacc[t] = __builtin_amdgcn_mfma_f32_16x16x32_bf16(af, bf_, oacc[t], 0, 0, 0);
        }
    }

    #pragma unroll
    for (int t = 0; t < 16; ++t) {
        const int n = (t * 4 + wave) * 16 + ln16;
        #pragma unroll
        for (int r = 0; r < 4; ++r) {
            int row = quad * 4 + r;
            out[(size_t)(b * NN + i0 + row) * DIM + n] = oacc[t][r];
        }
    }
}

// ---------------------------------------------------------------------------
extern "C" void kernel_launch(void* const* d_in, const int* in_sizes, int n_in,
                              void* d_out, int out_size, void* d_ws, size_t ws_size,
                              hipStream_t stream)
{
    (void)in_sizes; (void)n_in; (void)out_size; (void)ws_size;
    const float* x     = (const float*)d_in[0];
    const float* Wq    = (const float*)d_in[1];
    const float* Wk    = (const float*)d_in[2];
    const float* Wv    = (const float*)d_in[3];
    const float* pre   = (const float*)d_in[4];
    const float* post  = (const float*)d_in[5];
    const float* mem_k = (const float*)d_in[6];
    const float* mem_v = (const float*)d_in[7];
    const float* Wo    = (const float*)d_in[8];
    const float* bo    = (const float*)d_in[9];

    // workspace: K splits 3x bf16 [2][16][2064][64] = 25.4 MB
    //          + V f32 [2][16][2048][64] = 16.8 MB
    //          + partial top-8 (f32 val + i32 idx, JC=3) = 12.6 MB  -> 54.7 MB
    u16*   k_sp   = (u16*)d_ws;
    float* v_ws   = (float*)(k_sp + 3 * SPLITSZ);
    float* ws_val = v_ws + (size_t)BB * HS * NN * DH;
    int*   ws_idx = (int*)(ws_val + (size_t)BB * HS * NN * JC * 8);
    float* q_tmp  = (float*)d_out;                           // Q f32 [b*n][1024]

    prep_mem_kernel<<<128, 256, 0, stream>>>(mem_k, k_sp);

    dim3 gg(32, 16);
    gemm_kernel<<<gg, 256, 0, stream>>>(x, Wq, nullptr, q_tmp, 1);  // Q -> d_out
    gemm_kernel<<<gg, 256, 0, stream>>>(x, Wk, k_sp, nullptr, 2);   // K -> split planes
    gemm_kernel<<<gg, 256, 0, stream>>>(x, Wv, nullptr, v_ws, 0);   // V -> ws (f32)

    dim3 gs(JC, 128, 2);
    score_topk_kernel<<<gs, 256, 0, stream>>>(k_sp, (const float*)d_out,
                                              pre, ws_val, ws_idx);

    dim3 ga(128, 2);
    merge_pv_kernel<<<ga, 256, 0, stream>>>(v_ws, mem_v, ws_val, ws_idx,
                                            post, Wo, bo, (float*)d_out);
}

// Round 10
// 1241.727 us; speedup vs baseline: 2.3655x; 1.0858x over previous
//
#include <hip/hip_runtime.h>
#include <hip/hip_bf16.h>

typedef unsigned short u16;
typedef unsigned int   u32;

#define BB   2
#define NN   2048
#define HS   16
#define DH   64
#define NM   16
#define JT   2064   // NM + NN
#define DIM  1024
#define CT   26     // j-tiles per chunk (416 keys)
#define JC   5      // ceil(129/26)

#define SPLITSZ ((size_t)BB * HS * JT * DH)   // elements per K-split plane

__device__ __forceinline__ float bfval(u16 u) { return __uint_as_float(((u32)u) << 16); }
__device__ __forceinline__ float lo16(u32 u)  { return __uint_as_float(u << 16); }
__device__ __forceinline__ float hi16(u32 u)  { return __uint_as_float(u & 0xffff0000u); }
__device__ __forceinline__ u16 f2bf(float f)
{
    __hip_bfloat16 h = __float2bfloat16(f);
    return *(u16*)&h;
}

typedef __bf16 bf16x8 __attribute__((ext_vector_type(8)));
typedef float  f32x4  __attribute__((ext_vector_type(4)));

// ---------------------------------------------------------------------------
// mem_k rows -> K-split planes (hi/mid/lo bf16) at key rows 0..15.
// ---------------------------------------------------------------------------
__global__ void prep_mem_kernel(const float* __restrict__ mem_k, u16* __restrict__ k_sp)
{
    int t = blockIdx.x * 256 + threadIdx.x;          // 0 .. 32767
    int d = t & 63, j = (t >> 6) & 15, h = (t >> 10) & 15, b = (t >> 14) & 1;
    float x = mem_k[(h * NM + j) * DH + d];
    size_t di = ((size_t)(b * HS + h) * JT + j) * DH + d;
    u16 sh = f2bf(x);
    float d1 = x - bfval(sh);
    u16 sm = f2bf(d1);
    u16 sl = f2bf(d1 - bfval(sm));
    k_sp[di] = sh; k_sp[di + SPLITSZ] = sm; k_sp[di + 2 * SPLITSZ] = sl;
}

// ---------------------------------------------------------------------------
// Wo f32 [k][n] -> WoT bf16 [n][k] (B-frag native layout for the epilogue).
// ---------------------------------------------------------------------------
__global__ void prep_wot_kernel(const float* __restrict__ Wo, u16* __restrict__ wot)
{
    int t = blockIdx.x * 256 + threadIdx.x;          // 0 .. 1048575
    int k = t & 1023, n = t >> 10;
    wot[(size_t)n * 1024 + k] = f2bf(Wo[(size_t)k * 1024 + n]);
}

// ---------------------------------------------------------------------------
// Exact-f32 GEMM via 6-pass bf16 split MFMA (core verified R7-R9).
// mode 0: bf16 scatter to [b][h][2048][64] head layout (V)
// mode 1: f32 row-major C = acc (Q -> d_out)
// mode 2: K: split into hi/mid/lo bf16 planes, scatter [b][h][NM+i][64]
// ---------------------------------------------------------------------------
__global__ __launch_bounds__(256) void gemm_kernel(
    const float* __restrict__ A, const float* __restrict__ Bw,
    u16* __restrict__ dst16, float* __restrict__ dstf, int mode)
{
    __shared__ __align__(16) u16 a_h[128][32];
    __shared__ __align__(16) u16 a_m[128][32];
    __shared__ __align__(16) u16 a_l[128][32];
    __shared__ __align__(16) u16 b_hT[64][32];
    __shared__ __align__(16) u16 b_mT[64][32];
    __shared__ __align__(16) u16 b_lT[64][32];

    const int tid  = threadIdx.x;
    const int m0   = blockIdx.x * 128;
    const int n0   = blockIdx.y * 64;
    const int wave = tid >> 6, lane = tid & 63;
    const int ln16 = lane & 15, quad = lane >> 4;

    const int arow = tid >> 1;            // 0..127
    const int ac   = (tid & 1) * 16;      // 0 or 16
    const int brow = tid >> 3;            // 0..31
    const int bc   = (tid & 7) * 8;       // 0..56

    f32x4 acc[8] = {};

    for (int k0 = 0; k0 < 1024; k0 += 32) {
        float av[16];
        {
            const float4* ap = (const float4*)&A[(size_t)(m0 + arow) * 1024 + k0 + ac];
            *(float4*)&av[0]  = ap[0]; *(float4*)&av[4]  = ap[1];
            *(float4*)&av[8]  = ap[2]; *(float4*)&av[12] = ap[3];
        }
        float bv[8];
        {
            const float4* bp = (const float4*)&Bw[(size_t)(k0 + brow) * 1024 + n0 + bc];
            *(float4*)&bv[0] = bp[0]; *(float4*)&bv[4] = bp[1];
        }
        u16 ah[16], am[16], al[16], bh[8], bm[8], bl[8];
        #pragma unroll
        for (int e = 0; e < 16; ++e) {
            ah[e] = f2bf(av[e]);
            float d1 = av[e] - bfval(ah[e]);
            am[e] = f2bf(d1);
            al[e] = f2bf(d1 - bfval(am[e]));
        }
        #pragma unroll
        for (int e = 0; e < 8; ++e) {
            bh[e] = f2bf(bv[e]);
            float d1 = bv[e] - bfval(bh[e]);
            bm[e] = f2bf(d1);
            bl[e] = f2bf(d1 - bfval(bm[e]));
        }
        __syncthreads();
        *(uint4*)&a_h[arow][ac]     = ((uint4*)ah)[0];
        *(uint4*)&a_h[arow][ac + 8] = ((uint4*)ah)[1];
        *(uint4*)&a_m[arow][ac]     = ((uint4*)am)[0];
        *(uint4*)&a_m[arow][ac + 8] = ((uint4*)am)[1];
        *(uint4*)&a_l[arow][ac]     = ((uint4*)al)[0];
        *(uint4*)&a_l[arow][ac + 8] = ((uint4*)al)[1];
        #pragma unroll
        for (int e = 0; e < 8; ++e) {
            b_hT[bc + e][brow] = bh[e];
            b_mT[bc + e][brow] = bm[e];
            b_lT[bc + e][brow] = bl[e];
        }
        __syncthreads();

        bf16x8 a0h = *(const bf16x8*)&a_h[wave * 32 + ln16][quad * 8];
        bf16x8 a0m = *(const bf16x8*)&a_m[wave * 32 + ln16][quad * 8];
        bf16x8 a0l = *(const bf16x8*)&a_l[wave * 32 + ln16][quad * 8];
        bf16x8 a1h = *(const bf16x8*)&a_h[wave * 32 + 16 + ln16][quad * 8];
        bf16x8 a1m = *(const bf16x8*)&a_m[wave * 32 + 16 + ln16][quad * 8];
        bf16x8 a1l = *(const bf16x8*)&a_l[wave * 32 + 16 + ln16][quad * 8];
        #pragma unroll
        for (int c = 0; c < 4; ++c) {
            bf16x8 bh_ = *(const bf16x8*)&b_hT[c * 16 + ln16][quad * 8];
            bf16x8 bm_ = *(const bf16x8*)&b_mT[c * 16 + ln16][quad * 8];
            bf16x8 bl_ = *(const bf16x8*)&b_lT[c * 16 + ln16][quad * 8];
            acc[c]     = __builtin_amdgcn_mfma_f32_16x16x32_bf16(a0m, bm_, acc[c],     0, 0, 0);
            acc[c]     = __builtin_amdgcn_mfma_f32_16x16x32_bf16(a0h, bl_, acc[c],     0, 0, 0);
            acc[c]     = __builtin_amdgcn_mfma_f32_16x16x32_bf16(a0l, bh_, acc[c],     0, 0, 0);
            acc[c]     = __builtin_amdgcn_mfma_f32_16x16x32_bf16(a0h, bm_, acc[c],     0, 0, 0);
            acc[c]     = __builtin_amdgcn_mfma_f32_16x16x32_bf16(a0m, bh_, acc[c],     0, 0, 0);
            acc[c]     = __builtin_amdgcn_mfma_f32_16x16x32_bf16(a0h, bh_, acc[c],     0, 0, 0);
            acc[4 + c] = __builtin_amdgcn_mfma_f32_16x16x32_bf16(a1m, bm_, acc[4 + c], 0, 0, 0);
            acc[4 + c] = __builtin_amdgcn_mfma_f32_16x16x32_bf16(a1h, bl_, acc[4 + c], 0, 0, 0);
            acc[4 + c] = __builtin_amdgcn_mfma_f32_16x16x32_bf16(a1l, bh_, acc[4 + c], 0, 0, 0);
            acc[4 + c] = __builtin_amdgcn_mfma_f32_16x16x32_bf16(a1h, bm_, acc[4 + c], 0, 0, 0);
            acc[4 + c] = __builtin_amdgcn_mfma_f32_16x16x32_bf16(a1m, bh_, acc[4 + c], 0, 0, 0);
            acc[4 + c] = __builtin_amdgcn_mfma_f32_16x16x32_bf16(a1h, bh_, acc[4 + c], 0, 0, 0);
        }
    }

    #pragma unroll
    for (int hf = 0; hf < 2; ++hf) {
        #pragma unroll
        for (int c = 0; c < 4; ++c) {
            #pragma unroll
            for (int r = 0; r < 4; ++r) {
                int row = m0 + wave * 32 + hf * 16 + quad * 4 + r;
                int col = n0 + c * 16 + ln16;
                float v = acc[hf * 4 + c][r];
                if (mode == 1) {
                    dstf[(size_t)row * 1024 + col] = v;
                } else {
                    int b = row >> 11, i = row & 2047;
                    int hd = col >> 6, d = col & 63;
                    if (mode == 0) {
                        dst16[(((size_t)(b * HS + hd)) * NN + i) * DH + d] = f2bf(v);
                    } else {
                        size_t di = (((size_t)(b * HS + hd)) * JT + NM + i) * DH + d;
                        u16 sh = f2bf(v);
                        float d1 = v - bfval(sh);
                        u16 sm = f2bf(d1);
                        u16 sl = f2bf(d1 - bfval(sm));
                        dst16[di] = sh;
                        dst16[di + SPLITSZ] = sm;
                        dst16[di + 2 * SPLITSZ] = sl;
                    }
                }
            }
        }
    }
}

// ---------------------------------------------------------------------------
// Phase 1 (MFMA): scores + partial top-8 per j-chunk. (machinery = R9, CT=26)
// ---------------------------------------------------------------------------
__global__ __launch_bounds__(256) void score_topk_kernel(
    const u16* __restrict__ k_sp, const float* __restrict__ q_all,
    const float* __restrict__ pre,
    float* __restrict__ ws_val, u16* __restrict__ ws_idx)
{
    const int jc = blockIdx.x;
    const int iy = blockIdx.y;
    const int b  = blockIdx.z;
    const int ntiles = iy + 2;
    const int jt_lo = jc * CT;
    if (jt_lo >= ntiles) return;                 // block-uniform early exit
    const int jt_hi = min(jt_lo + CT, ntiles);

    __shared__ __align__(16) float fsm[8448];
    float* S  = fsm;            // [16][256]  MFMA C-layout scores per head
    float* MX = fsm + 4096;     // [16][256]  mixed scores [kk][ti*16+tj]
    float* pp = fsm + 8192;     // [256] pre_proj * 0.125

    const int tid  = threadIdx.x;
    const int i0   = iy * 16;
    const int wave = tid >> 6, lane = tid & 63;
    const int ln16 = lane & 15, quad = lane >> 4;

    pp[tid] = pre[tid] * 0.125f;

    // Q A-frags: 4 heads/wave x 2 K-halves x 3 splits, loaded once per block.
    bf16x8 qh[4][2], qm[4][2], ql[4][2];
    {
        const float* qrow = q_all + (size_t)(b * NN + i0 + ln16) * DIM;
        #pragma unroll
        for (int h4 = 0; h4 < 4; ++h4) {
            const int h = wave * 4 + h4;
            #pragma unroll
            for (int half = 0; half < 2; ++half) {
                const float* src = qrow + h * 64 + half * 32 + quad * 8;
                float4 u0 = *(const float4*)src;
                float4 u1 = *(const float4*)(src + 4);
                float xv[8] = {u0.x, u0.y, u0.z, u0.w, u1.x, u1.y, u1.z, u1.w};
                u16 eh[8], em[8], el[8];
                #pragma unroll
                for (int e = 0; e < 8; ++e) {
                    eh[e] = f2bf(xv[e]);
                    float d1 = xv[e] - bfval(eh[e]);
                    em[e] = f2bf(d1);
                    el[e] = f2bf(d1 - bfval(em[e]));
                }
                qh[h4][half] = *(bf16x8*)eh;
                qm[h4][half] = *(bf16x8*)em;
                ql[h4][half] = *(bf16x8*)el;
            }
        }
    }

    const int kk_r = tid & 15, ti_r = tid >> 4;
    float tv[8];
    int   tx[8];
    #pragma unroll
    for (int t = 0; t < 8; ++t) { tv[t] = -1e30f; tx[t] = 0; }
    const int jlim = NM + i0 + ti_r;

    for (int jt = jt_lo; jt < jt_hi; ++jt) {
        // scores via MFMA: wave w computes heads 4w..4w+3
        #pragma unroll
        for (int h4 = 0; h4 < 4; ++h4) {
            const int h = wave * 4 + h4;
            const u16* kb = k_sp + ((size_t)(b * HS + h) * JT + jt * 16 + ln16) * DH;
            f32x4 acc = {};
            #pragma unroll
            for (int half = 0; half < 2; ++half) {
                const u16* k0 = kb + half * 32 + quad * 8;
                bf16x8 kh_ = *(const bf16x8*)(k0);
                bf16x8 km_ = *(const bf16x8*)(k0 + SPLITSZ);
                bf16x8 kl_ = *(const bf16x8*)(k0 + 2 * SPLITSZ);
                acc = __builtin_amdgcn_mfma_f32_16x16x32_bf16(qm[h4][half], km_, acc, 0, 0, 0);
                acc = __builtin_amdgcn_mfma_f32_16x16x32_bf16(qh[h4][half], kl_, acc, 0, 0, 0);
                acc = __builtin_amdgcn_mfma_f32_16x16x32_bf16(ql[h4][half], kh_, acc, 0, 0, 0);
                acc = __builtin_amdgcn_mfma_f32_16x16x32_bf16(qh[h4][half], km_, acc, 0, 0, 0);
                acc = __builtin_amdgcn_mfma_f32_16x16x32_bf16(qm[h4][half], kh_, acc, 0, 0, 0);
                acc = __builtin_amdgcn_mfma_f32_16x16x32_bf16(qh[h4][half], kh_, acc, 0, 0, 0);
            }
            #pragma unroll
            for (int r = 0; r < 4; ++r)
                S[h * 256 + (quad * 4 + r) * 16 + ln16] = acc[r];
        }
        __syncthreads();

        // head mix: cell = tid; MX[kk][cell] = sum_h pp[h][kk]*S[h][cell]
        {
            float sv[16];
            #pragma unroll
            for (int h = 0; h < 16; ++h) sv[h] = S[h * 256 + tid];
            #pragma unroll
            for (int kk = 0; kk < 16; ++kk) {
                float mx = 0.f;
                #pragma unroll
                for (int h = 0; h < 16; ++h) mx += pp[h * 16 + kk] * sv[h];
                MX[kk * 256 + tid] = mx;
            }
        }
        __syncthreads();

        // top-8 update for row (kk_r, ti_r); rotate tj start by kk_r
        for (int s = 0; s < 16; ++s) {
            int tjj = (s + kk_r) & 15;
            int j = jt * 16 + tjj;
            if (j <= jlim) {
                float c = MX[kk_r * 256 + ti_r * 16 + tjj];
                if (c > tv[7]) {
                    #pragma unroll
                    for (int t = 7; t >= 1; --t) {
                        if (c > tv[t - 1])      { tv[t] = tv[t - 1]; tx[t] = tx[t - 1]; }
                        else if (c > tv[t])     { tv[t] = c;         tx[t] = j; }
                    }
                    if (c > tv[0]) { tv[0] = c; tx[0] = j; }
                }
            }
        }
        __syncthreads();
    }

    size_t base = ((((size_t)b * HS + kk_r) * NN + i0 + ti_r) * JC + jc) * 8;
    #pragma unroll
    for (int t = 0; t < 8; ++t) {
        ws_val[base + t] = tv[t];
        ws_idx[base + t] = (u16)tx[t];
    }
}

// ---------------------------------------------------------------------------
// Phase 2: merge partial top-8s -> softmax -> sparse PV (bf16 V ws, f32 mem_v)
// -> fused out-proj with pre-transposed bf16 WoT (vector B-frag loads).
// ---------------------------------------------------------------------------
__global__ __launch_bounds__(256) void merge_pv_kernel(
    const u16* __restrict__ v_bf, const float* __restrict__ mem_v,
    const float* __restrict__ ws_val, const u16* __restrict__ ws_idx,
    const float* __restrict__ post, const u16* __restrict__ wot,
    const float* __restrict__ bo, float* __restrict__ out)
{
    __shared__ __align__(16) float fsm[13312];
    float* dotsm = fsm + 8704;     // [4096]: w park [0..2047], j park [2048..4095]
    float* pp2   = fsm + 13056;    // [256] post_proj
    u16*   arows = (u16*)fsm;      // [16][1032] bf16 (PV rows)

    const int tid = threadIdx.x;
    const int b   = blockIdx.y;
    const int i0  = blockIdx.x * 16;
    const int ntiles = blockIdx.x + 2;
    const int jc_cnt = (ntiles + CT - 1) / CT;

    pp2[tid] = post[tid];

    const int kk_r = tid & 15, ti_r = tid >> 4;

    float tv[8];
    int   tx[8];
    #pragma unroll
    for (int t = 0; t < 8; ++t) { tv[t] = -1e30f; tx[t] = 0; }

    size_t rbase = (((size_t)b * HS + kk_r) * NN + i0 + ti_r) * JC;
    for (int jc = 0; jc < jc_cnt; ++jc) {
        #pragma unroll
        for (int t2 = 0; t2 < 8; ++t2) {
            float c = ws_val[(rbase + jc) * 8 + t2];
            int   j = ws_idx[(rbase + jc) * 8 + t2];
            if (c > tv[7]) {
                #pragma unroll
                for (int t = 7; t >= 1; --t) {
                    if (c > tv[t - 1])      { tv[t] = tv[t - 1]; tx[t] = tx[t - 1]; }
                    else if (c > tv[t])     { tv[t] = c;         tx[t] = j; }
                }
                if (c > tv[0]) { tv[0] = c; tx[0] = j; }
            }
        }
    }

    float m = tv[0];
    float wv[8], wsum = 0.f;
    #pragma unroll
    for (int t = 0; t < 8; ++t) { wv[t] = __expf(tv[t] - m); wsum += wv[t]; }
    float inv = 1.f / wsum;

    #pragma unroll
    for (int t = 0; t < 8; ++t) {
        dotsm[(kk_r * 16 + ti_r) * 8 + t]        = wv[t] * inv;
        dotsm[2048 + (kk_r * 16 + ti_r) * 8 + t] = __int_as_float(tx[t]);
    }
    __syncthreads();

    // PV: thread = (ti_o, k2)
    const int ti_o = tid >> 4, k2 = tid & 15;
    {
        float acc[64];
        #pragma unroll
        for (int d = 0; d < 64; ++d) acc[d] = 0.f;
        const u16*   vws_base  = v_bf  + (size_t)(b * HS + k2) * NN * DH;
        const float* vmem_base = mem_v + (size_t)k2 * NM * DH;

        for (int kk = 0; kk < 16; ++kk) {
            float p2 = pp2[kk * 16 + k2];
            for (int t = 0; t < 8; ++t) {
                float w = dotsm[(kk * 16 + ti_o) * 8 + t] * p2;
                int j = __float_as_int(dotsm[2048 + (kk * 16 + ti_o) * 8 + t]);
                if (j < NM) {
                    const float* vr = vmem_base + (size_t)j * DH;
                    #pragma unroll
                    for (int r = 0; r < 16; ++r) {
                        float4 u = *(const float4*)&vr[r * 4];
                        acc[r * 4 + 0] += w * u.x; acc[r * 4 + 1] += w * u.y;
                        acc[r * 4 + 2] += w * u.z; acc[r * 4 + 3] += w * u.w;
                    }
                } else {
                    const uint4* vr = (const uint4*)(vws_base + (size_t)(j - NM) * DH);
                    #pragma unroll
                    for (int r = 0; r < 8; ++r) {
                        uint4 u = vr[r];
                        acc[r * 8 + 0] += w * lo16(u.x); acc[r * 8 + 1] += w * hi16(u.x);
                        acc[r * 8 + 2] += w * lo16(u.y); acc[r * 8 + 3] += w * hi16(u.y);
                        acc[r * 8 + 4] += w * lo16(u.z); acc[r * 8 + 5] += w * hi16(u.z);
                        acc[r * 8 + 6] += w * lo16(u.w); acc[r * 8 + 7] += w * hi16(u.w);
                    }
                }
            }
        }
        #pragma unroll
        for (int d = 0; d < 64; ++d) {
            float o = acc[d];
            o = (o == o) ? o : 1e4f;             // V-side NaN sentinel (diagnostic)
            arows[ti_o * 1032 + k2 * 64 + d] = f2bf(o);
        }
    }
    __syncthreads();

    // fused out-projection: out_rows(16x1024) = arows(16x1024) @ Wo + bo
    const int wave = tid >> 6, lane = tid & 63;
    const int ln16 = lane & 15, quad = lane >> 4;

    f32x4 oacc[16];
    #pragma unroll
    for (int t = 0; t < 16; ++t) {
        float bv = bo[(t * 4 + wave) * 16 + ln16];
        oacc[t][0] = bv; oacc[t][1] = bv; oacc[t][2] = bv; oacc[t][3] = bv;
    }

    for (int k0 = 0; k0 < 1024; k0 += 32) {
        bf16x8 af = *(const bf16x8*)&arows[ln16 * 1032 + k0 + quad * 8];
        #pragma unroll
        for (int t = 0; t < 16; ++t) {
            const int n = (t * 4 + wave) * 16 + ln16;
            bf16x8 bf_ = *(const bf16x8*)&wot[(size_t)n * 1024 + k0 + quad * 8];
            oacc[t] = __builtin_amdgcn_mfma_f32_16x16x32_bf16(af, bf_, oacc[t], 0, 0, 0);
        }
    }

    #pragma unroll
    for (int t = 0; t < 16; ++t) {
        const int n = (t * 4 + wave) * 16 + ln16;
        #pragma unroll
        for (int r = 0; r < 4; ++r) {
            int row = quad * 4 + r;
            out[(size_t)(b * NN + i0 + row) * DIM + n] = oacc[t][r];
        }
    }
}

// ---------------------------------------------------------------------------
extern "C" void kernel_launch(void* const* d_in, const int* in_sizes, int n_in,
                              void* d_out, int out_size, void* d_ws, size_t ws_size,
                              hipStream_t stream)
{
    (void)in_sizes; (void)n_in; (void)out_size; (void)ws_size;
    const float* x     = (const float*)d_in[0];
    const float* Wq    = (const float*)d_in[1];
    const float* Wk    = (const float*)d_in[2];
    const float* Wv    = (const float*)d_in[3];
    const float* pre   = (const float*)d_in[4];
    const float* post  = (const float*)d_in[5];
    const float* mem_k = (const float*)d_in[6];
    const float* mem_v = (const float*)d_in[7];
    const float* Wo    = (const float*)d_in[8];
    const float* bo    = (const float*)d_in[9];

    // workspace (51.6 MB total, < 54.6 proven):
    //   K splits 3x bf16 [2][16][2064][64]            = 25.36 MB
    //   V bf16 [2][16][2048][64]                      =  8.39 MB
    //   partial top-8 val f32 [2][16][2048][JC=5][8]  = 10.49 MB
    //   partial top-8 idx u16                          =  5.24 MB
    //   WoT bf16 [1024][1024]                         =  2.10 MB
    u16*   k_sp   = (u16*)d_ws;
    u16*   v_bf   = k_sp + 3 * SPLITSZ;
    float* ws_val = (float*)(v_bf + (size_t)BB * HS * NN * DH);
    u16*   ws_idx = (u16*)(ws_val + (size_t)BB * HS * NN * JC * 8);
    u16*   wot    = ws_idx + (size_t)BB * HS * NN * JC * 8;
    float* q_tmp  = (float*)d_out;                           // Q f32 [b*n][1024]

    prep_mem_kernel<<<128, 256, 0, stream>>>(mem_k, k_sp);
    prep_wot_kernel<<<4096, 256, 0, stream>>>(Wo, wot);

    dim3 gg(32, 16);
    gemm_kernel<<<gg, 256, 0, stream>>>(x, Wq, nullptr, q_tmp, 1);  // Q -> d_out
    gemm_kernel<<<gg, 256, 0, stream>>>(x, Wk, k_sp, nullptr, 2);   // K -> split planes
    gemm_kernel<<<gg, 256, 0, stream>>>(x, Wv, v_bf, nullptr, 0);   // V -> bf16 ws

    dim3 gs(JC, 128, 2);
    score_topk_kernel<<<gs, 256, 0, stream>>>(k_sp, (const float*)d_out,
                                              pre, ws_val, ws_idx);

    dim3 ga(128, 2);
    merge_pv_kernel<<<ga, 256, 0, stream>>>(v_bf, mem_v, ws_val, ws_idx,
                                            post, wot, bo, (float*)d_out);
}